// Round 1
// baseline (599.844 us; speedup 1.0000x reference)
//
#include <hip/hip_runtime.h>
#include <math.h>

#define N_NODES 50000

// ---------------- CSR construction ----------------

__global__ void k_hist(const int* __restrict__ dst, int E, int* __restrict__ counts) {
    int e = blockIdx.x * blockDim.x + threadIdx.x;
    if (e < E) atomicAdd(&counts[dst[e]], 1);
}

__global__ void k_scan1(const int* __restrict__ counts, int n,
                        int* __restrict__ exbuf, int* __restrict__ partials) {
    __shared__ int tmp[256];
    int t = threadIdx.x;
    int i = blockIdx.x * 256 + t;
    int v = (i < n) ? counts[i] : 0;
    tmp[t] = v;
    __syncthreads();
    for (int off = 1; off < 256; off <<= 1) {
        int add = (t >= off) ? tmp[t - off] : 0;
        __syncthreads();
        tmp[t] += add;
        __syncthreads();
    }
    if (i < n) exbuf[i] = tmp[t] - v;   // per-block exclusive
    if (t == 255) partials[blockIdx.x] = tmp[255];
}

__global__ void k_scan2(int* __restrict__ partials, int nb) {
    __shared__ int tmp[256];
    int t = threadIdx.x;
    int v = (t < nb) ? partials[t] : 0;
    tmp[t] = v;
    __syncthreads();
    for (int off = 1; off < 256; off <<= 1) {
        int add = (t >= off) ? tmp[t - off] : 0;
        __syncthreads();
        tmp[t] += add;
        __syncthreads();
    }
    if (t < nb) partials[t] = tmp[t] - v;  // exclusive scan of block sums
}

__global__ void k_scan3(int* __restrict__ rowptr, const int* __restrict__ partials,
                        int n, int E, int* __restrict__ cursor) {
    int i = blockIdx.x * 256 + threadIdx.x;
    if (i < n) {
        int v = rowptr[i] + partials[blockIdx.x];
        rowptr[i] = v;
        cursor[i] = v;
    }
    if (i == 0) rowptr[n] = E;
}

__global__ void k_scatter(const int* __restrict__ src, const int* __restrict__ dst, int E,
                          int* __restrict__ cursor, int* __restrict__ esrc) {
    int e = blockIdx.x * blockDim.x + threadIdx.x;
    if (e < E) {
        int pos = atomicAdd(&cursor[dst[e]], 1);
        esrc[pos] = src[e];
    }
}

// ---------------- segment max (gather form) ----------------
// one block per node, one thread per feature; coalesced across feature dim

template <int F>
__global__ void k_seg_max(const float* __restrict__ feat, const int* __restrict__ rowptr,
                          const int* __restrict__ esrc, float* __restrict__ out) {
    int n = blockIdx.x;
    int f = threadIdx.x;
    int beg = rowptr[n], end = rowptr[n + 1];
    float m = -INFINITY;
    for (int e = beg; e < end; ++e) {
        int s = esrc[e];
        m = fmaxf(m, feat[(size_t)s * F + f]);
    }
    if (beg == end) m = 0.f;           // isolated nodes -> 0 (PyG semantics)
    out[(size_t)n * F + f] = m;
}

// ---------------- layer 1: h = relu([agg | x] @ [W1_l ; W1_r] + b1) ----------------
// fp32 GEMM, M x 256, K = 256 (concat of two 128 sources), 64x64 tile, BK=16

__global__ __launch_bounds__(256) void k_lin1(
        const float* __restrict__ A0, const float* __restrict__ A1,   // [M,128] each
        const float* __restrict__ W0, const float* __restrict__ W1,   // [128,256] each
        const float* __restrict__ bias, float* __restrict__ H, int M) {
    __shared__ float As[16][65];   // [k][m]
    __shared__ float Bs[16][64];   // [k][n]
    int tid = threadIdx.x;
    int ty = tid >> 4, tx = tid & 15;
    int m0 = blockIdx.y * 64, n0 = blockIdx.x * 64;

    float acc[4][4];
#pragma unroll
    for (int i = 0; i < 4; ++i)
#pragma unroll
        for (int j = 0; j < 4; ++j) acc[i][j] = 0.f;

    for (int k0 = 0; k0 < 256; k0 += 16) {
#pragma unroll
        for (int l = tid; l < 64 * 16; l += 256) {
            int m = l >> 4, k = l & 15;
            int row = m0 + m, kg = k0 + k;
            float v = 0.f;
            if (row < M)
                v = (kg < 128) ? A0[(size_t)row * 128 + kg]
                               : A1[(size_t)row * 128 + (kg - 128)];
            As[k][m] = v;
        }
#pragma unroll
        for (int l = tid; l < 16 * 64; l += 256) {
            int k = l >> 6, n = l & 63;
            int kg = k0 + k;
            Bs[k][n] = (kg < 128) ? W0[(size_t)kg * 256 + n0 + n]
                                  : W1[(size_t)(kg - 128) * 256 + n0 + n];
        }
        __syncthreads();
#pragma unroll
        for (int kk = 0; kk < 16; ++kk) {
            float a[4], b[4];
#pragma unroll
            for (int i = 0; i < 4; ++i) a[i] = As[kk][ty * 4 + i];
#pragma unroll
            for (int j = 0; j < 4; ++j) b[j] = Bs[kk][tx * 4 + j];
#pragma unroll
            for (int i = 0; i < 4; ++i)
#pragma unroll
                for (int j = 0; j < 4; ++j) acc[i][j] += a[i] * b[j];
        }
        __syncthreads();
    }

    int col0 = n0 + tx * 4;
#pragma unroll
    for (int i = 0; i < 4; ++i) {
        int row = m0 + ty * 4 + i;
        if (row < M) {
            float4 v;
            v.x = fmaxf(acc[i][0] + bias[col0 + 0], 0.f);
            v.y = fmaxf(acc[i][1] + bias[col0 + 1], 0.f);
            v.z = fmaxf(acc[i][2] + bias[col0 + 2], 0.f);
            v.w = fmaxf(acc[i][3] + bias[col0 + 3], 0.f);
            *(float4*)(H + (size_t)row * 256 + col0) = v;
        }
    }
}

// ---------------- layer 2: z = [agg2 | h] @ [W2_l ; W2_r] + b2 ----------------
// M x 32, K = 512 (concat of two 256 sources), 64x32 tile, BK=32

__global__ __launch_bounds__(256) void k_lin2(
        const float* __restrict__ A0, const float* __restrict__ A1,   // [M,256] each
        const float* __restrict__ W0, const float* __restrict__ W1,   // [256,32] each
        const float* __restrict__ bias, float* __restrict__ Z, int M) {
    __shared__ float As[32][65];   // [k][m]
    __shared__ float Bs[32][32];   // [k][n]
    int tid = threadIdx.x;
    int ty = tid >> 5, tx = tid & 31;   // ty in [0,8), tx = output col
    int m0 = blockIdx.x * 64;

    float acc[8];
#pragma unroll
    for (int i = 0; i < 8; ++i) acc[i] = 0.f;

    for (int k0 = 0; k0 < 512; k0 += 32) {
#pragma unroll
        for (int l = tid; l < 64 * 32; l += 256) {
            int m = l >> 5, k = l & 31;
            int row = m0 + m, kg = k0 + k;
            float v = 0.f;
            if (row < M)
                v = (kg < 256) ? A0[(size_t)row * 256 + kg]
                               : A1[(size_t)row * 256 + (kg - 256)];
            As[k][m] = v;
        }
#pragma unroll
        for (int l = tid; l < 32 * 32; l += 256) {
            int k = l >> 5, n = l & 31;
            int kg = k0 + k;
            Bs[k][n] = (kg < 256) ? W0[(size_t)kg * 32 + n]
                                  : W1[(size_t)(kg - 256) * 32 + n];
        }
        __syncthreads();
#pragma unroll
        for (int kk = 0; kk < 32; ++kk) {
            float b = Bs[kk][tx];
#pragma unroll
            for (int i = 0; i < 8; ++i) acc[i] += As[kk][ty + 8 * i] * b;
        }
        __syncthreads();
    }

#pragma unroll
    for (int i = 0; i < 8; ++i) {
        int row = m0 + ty + 8 * i;
        if (row < M) Z[(size_t)row * 32 + tx] = acc[i] + bias[tx];
    }
}

// ---------------- decode: out[e] = dot(z[s], z[d]) over 32 dims ----------------
// 8 lanes per edge, float4 loads, shuffle reduce

__global__ void k_decode(const float* __restrict__ z, const int* __restrict__ eli,
                         int EL, float* __restrict__ out) {
    int tid = blockIdx.x * blockDim.x + threadIdx.x;
    int e = tid >> 3, lane = tid & 7;
    if (e >= EL) return;
    int s = eli[e], d = eli[EL + e];
    float4 a = *((const float4*)(z + (size_t)s * 32) + lane);
    float4 b = *((const float4*)(z + (size_t)d * 32) + lane);
    float dot = a.x * b.x + a.y * b.y + a.z * b.z + a.w * b.w;
    dot += __shfl_xor(dot, 1);
    dot += __shfl_xor(dot, 2);
    dot += __shfl_xor(dot, 4);
    if (lane == 0) out[e] = dot;
}

// ---------------- launch ----------------

extern "C" void kernel_launch(void* const* d_in, const int* in_sizes, int n_in,
                              void* d_out, int out_size, void* d_ws, size_t ws_size,
                              hipStream_t stream) {
    const float* x   = (const float*)d_in[0];
    const int*   ei  = (const int*)d_in[1];
    const int*   eli = (const int*)d_in[2];
    const float* W1l = (const float*)d_in[3];
    const float* b1  = (const float*)d_in[4];
    const float* W1r = (const float*)d_in[5];
    const float* W2l = (const float*)d_in[6];
    const float* b2  = (const float*)d_in[7];
    const float* W2r = (const float*)d_in[8];
    float* out = (float*)d_out;

    const int N  = N_NODES;
    const int E  = in_sizes[1] / 2;
    const int EL = in_sizes[2] / 2;
    const int* src = ei;
    const int* dst = ei + E;

    char* ws = (char*)d_ws;
    size_t off = 0;
    auto alloc = [&](size_t bytes) -> void* {
        void* p = ws + off;
        off += (bytes + 255) & ~(size_t)255;
        return p;
    };
    float* agg    = (float*)alloc((size_t)N * 256 * 4);  // reused: [N,128] L1, [N,256] L2
    float* hbuf   = (float*)alloc((size_t)N * 256 * 4);
    float* zbuf   = (float*)alloc((size_t)N * 32 * 4);
    int* rowptr   = (int*)alloc((size_t)(N + 1) * 4);
    int* cursor   = (int*)alloc((size_t)N * 4);          // counts, then write cursor
    int* esrc     = (int*)alloc((size_t)E * 4);
    int* partials = (int*)alloc(256 * 4);

    const int tb = 256;
    const int nb = (N + 255) / 256;

    hipMemsetAsync(cursor, 0, (size_t)N * 4, stream);
    k_hist<<<(E + tb - 1) / tb, tb, 0, stream>>>(dst, E, cursor);
    k_scan1<<<nb, 256, 0, stream>>>(cursor, N, rowptr, partials);
    k_scan2<<<1, 256, 0, stream>>>(partials, nb);
    k_scan3<<<nb, 256, 0, stream>>>(rowptr, partials, N, E, cursor);
    k_scatter<<<(E + tb - 1) / tb, tb, 0, stream>>>(src, dst, E, cursor, esrc);

    // layer 1
    k_seg_max<128><<<N, 128, 0, stream>>>(x, rowptr, esrc, agg);
    dim3 g1(256 / 64, (N + 63) / 64);
    k_lin1<<<g1, 256, 0, stream>>>(agg, x, W1l, W1r, b1, hbuf, N);

    // layer 2
    k_seg_max<256><<<N, 256, 0, stream>>>(hbuf, rowptr, esrc, agg);
    k_lin2<<<(N + 63) / 64, 256, 0, stream>>>(agg, hbuf, W2l, W2r, b2, zbuf, N);

    // decode
    int dec_threads = EL * 8;
    k_decode<<<(dec_threads + 255) / 256, 256, 0, stream>>>(zbuf, eli, EL, out);
}

// Round 2
// 329.882 us; speedup vs baseline: 1.8184x; 1.8184x over previous
//
#include <hip/hip_runtime.h>
#include <hip/hip_bf16.h>
#include <math.h>

#define N_NODES 50000

typedef __attribute__((ext_vector_type(8))) short short8;   // 8 bf16 = 4 VGPRs
typedef __attribute__((ext_vector_type(4))) float f32x4;

static __device__ __forceinline__ float b2f(unsigned int u16) {
    union { unsigned int i; float f; } c; c.i = u16 << 16; return c.f;
}
static __device__ __forceinline__ unsigned int fbits(float f) {
    union { float f; unsigned int i; } c; c.f = f; return c.i;
}
static __device__ __forceinline__ unsigned short f2b_rne(float f) {
    // round-to-nearest-even bf16
    unsigned int u = fbits(f);
    u += 0x7fff + ((u >> 16) & 1);
    return (unsigned short)(u >> 16);
}

// ---------------- CSR construction ----------------

__global__ void k_hist(const int* __restrict__ dst, int E, int* __restrict__ counts) {
    int e = blockIdx.x * blockDim.x + threadIdx.x;
    if (e < E) atomicAdd(&counts[dst[e]], 1);
}

__global__ void k_scan1(const int* __restrict__ counts, int n,
                        int* __restrict__ exbuf, int* __restrict__ partials) {
    __shared__ int tmp[256];
    int t = threadIdx.x;
    int i = blockIdx.x * 256 + t;
    int v = (i < n) ? counts[i] : 0;
    tmp[t] = v;
    __syncthreads();
    for (int off = 1; off < 256; off <<= 1) {
        int add = (t >= off) ? tmp[t - off] : 0;
        __syncthreads();
        tmp[t] += add;
        __syncthreads();
    }
    if (i < n) exbuf[i] = tmp[t] - v;
    if (t == 255) partials[blockIdx.x] = tmp[255];
}

__global__ void k_scan2(int* __restrict__ partials, int nb) {
    __shared__ int tmp[256];
    int t = threadIdx.x;
    int v = (t < nb) ? partials[t] : 0;
    tmp[t] = v;
    __syncthreads();
    for (int off = 1; off < 256; off <<= 1) {
        int add = (t >= off) ? tmp[t - off] : 0;
        __syncthreads();
        tmp[t] += add;
        __syncthreads();
    }
    if (t < nb) partials[t] = tmp[t] - v;
}

__global__ void k_scan3(int* __restrict__ rowptr, const int* __restrict__ partials,
                        int n, int E, int* __restrict__ cursor) {
    int i = blockIdx.x * 256 + threadIdx.x;
    if (i < n) {
        int v = rowptr[i] + partials[blockIdx.x];
        rowptr[i] = v;
        cursor[i] = v;
    }
    if (i == 0) rowptr[n] = E;
}

__global__ void k_scatter(const int* __restrict__ src, const int* __restrict__ dst, int E,
                          int* __restrict__ cursor, int* __restrict__ esrc) {
    int e = blockIdx.x * blockDim.x + threadIdx.x;
    if (e < E) {
        int pos = atomicAdd(&cursor[dst[e]], 1);
        esrc[pos] = src[e];
    }
}

// ---------------- casts ----------------

// x fp32 [N*128] -> bf16, 4 elems/thread
__global__ void k_cast_x(const float* __restrict__ x, unsigned short* __restrict__ xb, int n4) {
    int i = blockIdx.x * blockDim.x + threadIdx.x;
    if (i >= n4) return;
    float4 v = *(const float4*)(x + (size_t)i * 4);
    ushort4 o;
    o.x = f2b_rne(v.x); o.y = f2b_rne(v.y); o.z = f2b_rne(v.z); o.w = f2b_rne(v.w);
    *(ushort4*)(xb + (size_t)i * 4) = o;
}

// WT1[n][k] (bf16, [256][256]) = k<128 ? W1l[k][n] : W1r[k-128][n]
__global__ void k_cast_w1(const float* __restrict__ Wl, const float* __restrict__ Wr,
                          unsigned short* __restrict__ wt) {
    int i = blockIdx.x * blockDim.x + threadIdx.x;   // 65536
    int n = i >> 8, k = i & 255;
    float v = (k < 128) ? Wl[(size_t)k * 256 + n] : Wr[(size_t)(k - 128) * 256 + n];
    wt[(size_t)n * 256 + k] = f2b_rne(v);
}

// WT2[n][k] (bf16, [32][512]) = k<256 ? W2l[k][n] : W2r[k-256][n]
__global__ void k_cast_w2(const float* __restrict__ Wl, const float* __restrict__ Wr,
                          unsigned short* __restrict__ wt) {
    int i = blockIdx.x * blockDim.x + threadIdx.x;   // 16384
    int n = i >> 9, k = i & 511;
    float v = (k < 256) ? Wl[(size_t)k * 32 + n] : Wr[(size_t)(k - 256) * 32 + n];
    wt[(size_t)n * 512 + k] = f2b_rne(v);
}

// ---------------- segment max (bf16 gather) ----------------
// layer1: F=128, 64 threads, 2 feats/thread (uint = 2 bf16)

__global__ void k_seg_max1(const unsigned short* __restrict__ feat, const int* __restrict__ rowptr,
                           const int* __restrict__ esrc, unsigned short* __restrict__ out) {
    int n = blockIdx.x;
    int t = threadIdx.x;
    int beg = rowptr[n], end = rowptr[n + 1];
    float m0 = -INFINITY, m1 = -INFINITY;
    int e = beg;
    for (; e + 1 < end; e += 2) {
        int s0 = esrc[e], s1 = esrc[e + 1];
        unsigned int v0 = *(const unsigned int*)(feat + (size_t)s0 * 128 + 2 * t);
        unsigned int v1 = *(const unsigned int*)(feat + (size_t)s1 * 128 + 2 * t);
        m0 = fmaxf(m0, fmaxf(b2f(v0 & 0xffff), b2f(v1 & 0xffff)));
        m1 = fmaxf(m1, fmaxf(b2f(v0 >> 16), b2f(v1 >> 16)));
    }
    if (e < end) {
        int s0 = esrc[e];
        unsigned int v0 = *(const unsigned int*)(feat + (size_t)s0 * 128 + 2 * t);
        m0 = fmaxf(m0, b2f(v0 & 0xffff));
        m1 = fmaxf(m1, b2f(v0 >> 16));
    }
    if (beg == end) { m0 = 0.f; m1 = 0.f; }
    unsigned int packed = (fbits(m0) >> 16) | (fbits(m1) & 0xffff0000u);  // exact (inputs are bf16)
    *(unsigned int*)(out + (size_t)n * 128 + 2 * t) = packed;
}

// layer2: F=256, 64 threads, 4 feats/thread (uint2 = 4 bf16)

__global__ void k_seg_max2(const unsigned short* __restrict__ feat, const int* __restrict__ rowptr,
                           const int* __restrict__ esrc, unsigned short* __restrict__ out) {
    int n = blockIdx.x;
    int t = threadIdx.x;
    int beg = rowptr[n], end = rowptr[n + 1];
    float m0 = -INFINITY, m1 = -INFINITY, m2 = -INFINITY, m3 = -INFINITY;
    int e = beg;
    for (; e + 1 < end; e += 2) {
        int s0 = esrc[e], s1 = esrc[e + 1];
        uint2 v0 = *(const uint2*)(feat + (size_t)s0 * 256 + 4 * t);
        uint2 v1 = *(const uint2*)(feat + (size_t)s1 * 256 + 4 * t);
        m0 = fmaxf(m0, fmaxf(b2f(v0.x & 0xffff), b2f(v1.x & 0xffff)));
        m1 = fmaxf(m1, fmaxf(b2f(v0.x >> 16),   b2f(v1.x >> 16)));
        m2 = fmaxf(m2, fmaxf(b2f(v0.y & 0xffff), b2f(v1.y & 0xffff)));
        m3 = fmaxf(m3, fmaxf(b2f(v0.y >> 16),   b2f(v1.y >> 16)));
    }
    if (e < end) {
        int s0 = esrc[e];
        uint2 v0 = *(const uint2*)(feat + (size_t)s0 * 256 + 4 * t);
        m0 = fmaxf(m0, b2f(v0.x & 0xffff));
        m1 = fmaxf(m1, b2f(v0.x >> 16));
        m2 = fmaxf(m2, b2f(v0.y & 0xffff));
        m3 = fmaxf(m3, b2f(v0.y >> 16));
    }
    if (beg == end) { m0 = m1 = m2 = m3 = 0.f; }
    uint2 packed;
    packed.x = (fbits(m0) >> 16) | (fbits(m1) & 0xffff0000u);
    packed.y = (fbits(m2) >> 16) | (fbits(m3) & 0xffff0000u);
    *(uint2*)(out + (size_t)n * 256 + 4 * t) = packed;
}

// ---------------- layer 1 MFMA GEMM ----------------
// H = relu([aggb | xb] @ WT1^T + b1), A: [M,256] bf16 (two [M,128] halves),
// WT1: [256 n][256 k] bf16.  Tile 128x128, BK=32, 4 waves, each 64x64 (4x4 frags).

__global__ __launch_bounds__(256) void k_lin1_mfma(
        const unsigned short* __restrict__ A0, const unsigned short* __restrict__ A1,
        const unsigned short* __restrict__ WT, const float* __restrict__ bias,
        unsigned short* __restrict__ H, int M) {
    __shared__ short As[128 * 40];   // row stride 40 shorts (80B) to break bank conflicts
    __shared__ short Bs[128 * 40];

    int tid = threadIdx.x;
    int m0 = blockIdx.y * 128, n0 = blockIdx.x * 128;
    int L = tid & 63, wv = tid >> 6;
    int wr = wv >> 1, wc = wv & 1;
    int lane16 = L & 15, q = L >> 4;

    f32x4 acc[4][4];
#pragma unroll
    for (int i = 0; i < 4; ++i)
#pragma unroll
        for (int j = 0; j < 4; ++j) acc[i][j] = (f32x4){0.f, 0.f, 0.f, 0.f};

    for (int k0 = 0; k0 < 256; k0 += 32) {
        const unsigned short* Abase = (k0 < 128) ? A0 : A1;
        int kc = k0 & 127;
        // stage A: 128 rows x 32 k (4 segs of 8 bf16) = 512 segs, 2 per thread
#pragma unroll
        for (int s = tid; s < 512; s += 256) {
            int m = s >> 2, sg = s & 3;
            int row = m0 + m;
            float4 v = {0.f, 0.f, 0.f, 0.f};
            if (row < M) v = *(const float4*)(Abase + (size_t)row * 128 + kc + sg * 8);
            *(float4*)&As[m * 40 + sg * 8] = v;
        }
        // stage B (transposed weights): rows = n (128), cols = k (32)
#pragma unroll
        for (int s = tid; s < 512; s += 256) {
            int n = s >> 2, sg = s & 3;
            *(float4*)&Bs[n * 40 + sg * 8] =
                *(const float4*)(WT + (size_t)(n0 + n) * 256 + k0 + sg * 8);
        }
        __syncthreads();

        short8 a[4], b[4];
#pragma unroll
        for (int i = 0; i < 4; ++i)
            a[i] = *(const short8*)&As[(wr * 64 + i * 16 + lane16) * 40 + q * 8];
#pragma unroll
        for (int j = 0; j < 4; ++j)
            b[j] = *(const short8*)&Bs[(wc * 64 + j * 16 + lane16) * 40 + q * 8];
#pragma unroll
        for (int i = 0; i < 4; ++i)
#pragma unroll
            for (int j = 0; j < 4; ++j)
                acc[i][j] = __builtin_amdgcn_mfma_f32_16x16x32_bf16(a[i], b[j], acc[i][j], 0, 0, 0);
        __syncthreads();
    }

    // epilogue: D mapping col = lane16, row = q*4 + r
#pragma unroll
    for (int i = 0; i < 4; ++i) {
#pragma unroll
        for (int r = 0; r < 4; ++r) {
            int row = m0 + wr * 64 + i * 16 + q * 4 + r;
            if (row >= M) continue;
#pragma unroll
            for (int j = 0; j < 4; ++j) {
                int col = n0 + wc * 64 + j * 16 + lane16;
                float v = fmaxf(acc[i][j][r] + bias[col], 0.f);
                H[(size_t)row * 256 + col] = f2b_rne(v);
            }
        }
    }
}

// ---------------- layer 2 MFMA GEMM ----------------
// Z = [agg2b | hb] @ WT2^T + b2, A: [M,512] bf16 (two [M,256] halves),
// WT2: [32 n][512 k] bf16, Z fp32 [M,32]. Tile 128x32, BK=32, 4 waves each 32x32.

__global__ __launch_bounds__(256) void k_lin2_mfma(
        const unsigned short* __restrict__ A0, const unsigned short* __restrict__ A1,
        const unsigned short* __restrict__ WT, const float* __restrict__ bias,
        float* __restrict__ Z, int M) {
    __shared__ short As[128 * 40];
    __shared__ short Bs[32 * 40];

    int tid = threadIdx.x;
    int m0 = blockIdx.x * 128;
    int L = tid & 63, wv = tid >> 6;
    int lane16 = L & 15, q = L >> 4;

    f32x4 acc[2][2];
#pragma unroll
    for (int i = 0; i < 2; ++i)
#pragma unroll
        for (int j = 0; j < 2; ++j) acc[i][j] = (f32x4){0.f, 0.f, 0.f, 0.f};

    for (int k0 = 0; k0 < 512; k0 += 32) {
        const unsigned short* Abase = (k0 < 256) ? A0 : A1;
        int kc = k0 & 255;
#pragma unroll
        for (int s = tid; s < 512; s += 256) {
            int m = s >> 2, sg = s & 3;
            int row = m0 + m;
            float4 v = {0.f, 0.f, 0.f, 0.f};
            if (row < M) v = *(const float4*)(Abase + (size_t)row * 256 + kc + sg * 8);
            *(float4*)&As[m * 40 + sg * 8] = v;
        }
        if (tid < 128) {
            int n = tid >> 2, sg = tid & 3;
            *(float4*)&Bs[n * 40 + sg * 8] =
                *(const float4*)(WT + (size_t)n * 512 + k0 + sg * 8);
        }
        __syncthreads();

        short8 a[2], b[2];
#pragma unroll
        for (int i = 0; i < 2; ++i)
            a[i] = *(const short8*)&As[(wv * 32 + i * 16 + lane16) * 40 + q * 8];
#pragma unroll
        for (int j = 0; j < 2; ++j)
            b[j] = *(const short8*)&Bs[(j * 16 + lane16) * 40 + q * 8];
#pragma unroll
        for (int i = 0; i < 2; ++i)
#pragma unroll
            for (int j = 0; j < 2; ++j)
                acc[i][j] = __builtin_amdgcn_mfma_f32_16x16x32_bf16(a[i], b[j], acc[i][j], 0, 0, 0);
        __syncthreads();
    }

#pragma unroll
    for (int i = 0; i < 2; ++i) {
#pragma unroll
        for (int r = 0; r < 4; ++r) {
            int row = m0 + wv * 32 + i * 16 + q * 4 + r;
            if (row >= M) continue;
#pragma unroll
            for (int j = 0; j < 2; ++j) {
                int col = j * 16 + lane16;
                Z[(size_t)row * 32 + col] = acc[i][j][r] + bias[col];
            }
        }
    }
}

// ---------------- decode ----------------

__global__ void k_decode(const float* __restrict__ z, const int* __restrict__ eli,
                         int EL, float* __restrict__ out) {
    int tid = blockIdx.x * blockDim.x + threadIdx.x;
    int e = tid >> 3, lane = tid & 7;
    if (e >= EL) return;
    int s = eli[e], d = eli[EL + e];
    float4 a = *((const float4*)(z + (size_t)s * 32) + lane);
    float4 b = *((const float4*)(z + (size_t)d * 32) + lane);
    float dot = a.x * b.x + a.y * b.y + a.z * b.z + a.w * b.w;
    dot += __shfl_xor(dot, 1);
    dot += __shfl_xor(dot, 2);
    dot += __shfl_xor(dot, 4);
    if (lane == 0) out[e] = dot;
}

// ---------------- launch ----------------

extern "C" void kernel_launch(void* const* d_in, const int* in_sizes, int n_in,
                              void* d_out, int out_size, void* d_ws, size_t ws_size,
                              hipStream_t stream) {
    const float* x   = (const float*)d_in[0];
    const int*   ei  = (const int*)d_in[1];
    const int*   eli = (const int*)d_in[2];
    const float* W1l = (const float*)d_in[3];
    const float* b1  = (const float*)d_in[4];
    const float* W1r = (const float*)d_in[5];
    const float* W2l = (const float*)d_in[6];
    const float* b2  = (const float*)d_in[7];
    const float* W2r = (const float*)d_in[8];
    float* out = (float*)d_out;

    const int N  = N_NODES;
    const int E  = in_sizes[1] / 2;
    const int EL = in_sizes[2] / 2;
    const int* src = ei;
    const int* dst = ei + E;

    char* ws = (char*)d_ws;
    size_t off = 0;
    auto alloc = [&](size_t bytes) -> void* {
        void* p = ws + off;
        off += (bytes + 255) & ~(size_t)255;
        return p;
    };
    unsigned short* xb   = (unsigned short*)alloc((size_t)N * 128 * 2);
    unsigned short* aggb = (unsigned short*)alloc((size_t)N * 256 * 2);  // L1 uses 128, L2 uses 256
    unsigned short* hb   = (unsigned short*)alloc((size_t)N * 256 * 2);
    float* zbuf          = (float*)alloc((size_t)N * 32 * 4);
    unsigned short* wt1  = (unsigned short*)alloc(256 * 256 * 2);
    unsigned short* wt2  = (unsigned short*)alloc(32 * 512 * 2);
    int* rowptr   = (int*)alloc((size_t)(N + 1) * 4);
    int* cursor   = (int*)alloc((size_t)N * 4);
    int* esrc     = (int*)alloc((size_t)E * 4);
    int* partials = (int*)alloc(256 * 4);

    const int tb = 256;
    const int nb = (N + 255) / 256;

    // casts (independent of CSR)
    k_cast_x<<<(N * 128 / 4 + 255) / 256, 256, 0, stream>>>(x, xb, N * 128 / 4);
    k_cast_w1<<<65536 / 256, 256, 0, stream>>>(W1l, W1r, wt1);
    k_cast_w2<<<16384 / 256, 256, 0, stream>>>(W2l, W2r, wt2);

    // CSR
    hipMemsetAsync(cursor, 0, (size_t)N * 4, stream);
    k_hist<<<(E + tb - 1) / tb, tb, 0, stream>>>(dst, E, cursor);
    k_scan1<<<nb, 256, 0, stream>>>(cursor, N, rowptr, partials);
    k_scan2<<<1, 256, 0, stream>>>(partials, nb);
    k_scan3<<<nb, 256, 0, stream>>>(rowptr, partials, N, E, cursor);
    k_scatter<<<(E + tb - 1) / tb, tb, 0, stream>>>(src, dst, E, cursor, esrc);

    // layer 1
    k_seg_max1<<<N, 64, 0, stream>>>(xb, rowptr, esrc, aggb);
    dim3 g1(2, (N + 127) / 128);
    k_lin1_mfma<<<g1, 256, 0, stream>>>(aggb, xb, wt1, b1, hb, N);

    // layer 2
    k_seg_max2<<<N, 64, 0, stream>>>(hb, rowptr, esrc, aggb);
    k_lin2_mfma<<<(N + 127) / 128, 256, 0, stream>>>(aggb, hb, wt2, b2, zbuf, N);

    // decode
    k_decode<<<(EL * 8 + 255) / 256, 256, 0, stream>>>(zbuf, eli, EL, out);
}